// Round 1
// baseline (118.961 us; speedup 1.0000x reference)
//
#include <hip/hip_runtime.h>
#include <cstdint>

// AnchorTargetLayer: T = 160*160*9 anchors vs M = 128 gt boxes.
// Output (T,7): [label, t0..t3, inside_w, outside_w], float32, row-major.

#define T_TOTAL 230400
#define W_ 160
#define A_ 9
#define M_ 128
#define NBINS 4096
#define BCAP 1024
#define KFG 128
#define BATCH 256

struct Ws {
  int gt_max_bits[M_];        // signed-int float bits; -1 == "empty" (== ov -1 rows)
  int fg_count, bg_count;
  int bnd_fg_n, bnd_bg_n;
  int sel_fg, b_fg, cb_fg;    // selection-needed flag, boundary bucket, count-before
  int sel_bg, b_bg, cb_bg, k_bg;
  float cut_fg_val; int cut_fg_idx;
  float cut_bg_val; int cut_bg_idx;
  float wgt;
  int hist_fg[NBINS], hist_bg[NBINS];
  float bnd_fg_val[BCAP]; int bnd_fg_idx[BCAP];
  float bnd_bg_val[BCAP]; int bnd_bg_idx[BCAP];
};

// Strict IEEE fp32 ops, no contraction — must match numpy/XLA rounding exactly.
__device__ __forceinline__ float fA(float a, float b) { return __fadd_rn(a, b); }
__device__ __forceinline__ float fS(float a, float b) { return __fsub_rn(a, b); }
__device__ __forceinline__ float fM(float a, float b) { return __fmul_rn(a, b); }
__device__ __forceinline__ float fD(float a, float b) { return __fdiv_rn(a, b); }

__device__ __forceinline__ float iou_f(float ax1, float ay1, float ax2, float ay2, float aarea,
                                       float gx1, float gy1, float gx2, float gy2, float garea) {
  float iw = fA(fS(fminf(ax2, gx2), fmaxf(ax1, gx1)), 1.0f);
  float ih = fA(fS(fminf(ay2, gy2), fmaxf(ay1, gy1)), 1.0f);
  float inter = fM(fmaxf(iw, 0.0f), fmaxf(ih, 0.0f));
  float uni = fS(fA(aarea, garea), inter);
  return fD(inter, uni);
}

__device__ __forceinline__ int bucket_of(float v) {
  int b = (int)(v * 4096.0f);
  return b > (NBINS - 1) ? (NBINS - 1) : (b < 0 ? 0 : b);
}

// Recompute anchor geometry for thread's anchor i.
__device__ __forceinline__ void anchor_coords(int i, const float* sa, float fs,
                                              float& ax1, float& ay1, float& ax2, float& ay2) {
  int s = i / A_, a = i - s * A_;
  int x = s % W_, y = s / W_;
  float shx = fM((float)x, fs), shy = fM((float)y, fs);
  ax1 = fA(sa[a * 4 + 0], shx);
  ay1 = fA(sa[a * 4 + 1], shy);
  ax2 = fA(sa[a * 4 + 2], shx);
  ay2 = fA(sa[a * 4 + 3], shy);
}

__global__ __launch_bounds__(256) void k_init(Ws* ws) {
  int t = blockIdx.x * blockDim.x + threadIdx.x;
  int n = gridDim.x * blockDim.x;
  for (int i = t; i < NBINS; i += n) { ws->hist_fg[i] = 0; ws->hist_bg[i] = 0; }
  for (int i = t; i < M_; i += n) ws->gt_max_bits[i] = -1;
  if (t == 0) {
    ws->fg_count = 0; ws->bg_count = 0;
    ws->bnd_fg_n = 0; ws->bnd_bg_n = 0;
    ws->cut_fg_val = 2.0f; ws->cut_fg_idx = 0x7fffffff;
    ws->cut_bg_val = 2.0f; ws->cut_bg_idx = 0x7fffffff;
  }
}

// Sweep 1: per-gt max IoU over all anchors (ov == -1 rows for outside anchors
// can never raise the max above the -1 init, so they are skipped).
__global__ __launch_bounds__(256) void k_gtmax(const float* gt, const float* im_info,
                                               const float* anchors, const int* fsp, Ws* ws) {
  __shared__ float sg[5][M_];
  __shared__ float sa[A_ * 4];
  __shared__ int smax[M_];
  int tid = threadIdx.x;
  if (tid < M_) {
    float x1 = gt[tid * 5 + 0], y1 = gt[tid * 5 + 1];
    float x2 = gt[tid * 5 + 2], y2 = gt[tid * 5 + 3];
    sg[0][tid] = x1; sg[1][tid] = y1; sg[2][tid] = x2; sg[3][tid] = y2;
    sg[4][tid] = fM(fA(fS(x2, x1), 1.0f), fA(fS(y2, y1), 1.0f));
    smax[tid] = -1;
  }
  if (tid < A_ * 4) sa[tid] = anchors[tid];
  __syncthreads();

  int i = blockIdx.x * 256 + tid;
  if (i < T_TOTAL) {
    float fs = (float)fsp[0];
    float ax1, ay1, ax2, ay2;
    anchor_coords(i, sa, fs, ax1, ay1, ax2, ay2);
    float imh = im_info[0], imw = im_info[1];
    bool inside = (ax1 >= 0.0f) && (ay1 >= 0.0f) && (ax2 < imw) && (ay2 < imh);
    if (inside) {
      float aarea = fM(fA(fS(ax2, ax1), 1.0f), fA(fS(ay2, ay1), 1.0f));
      for (int jj = 0; jj < M_; ++jj) {
        int j = (jj + tid) & (M_ - 1);  // rotate to spread LDS atomic addresses
        float ov = iou_f(ax1, ay1, ax2, ay2, aarea,
                         sg[0][j], sg[1][j], sg[2][j], sg[3][j], sg[4][j]);
        atomicMax(&smax[j], __float_as_int(ov));  // ov >= 0 -> bits monotone as signed int
      }
    }
  }
  __syncthreads();
  if (tid < M_ && smax[tid] >= 0) atomicMax(&ws->gt_max_bits[tid], smax[tid]);
}

// Sweep 2: per-anchor max/argmax, is_best (exact equality vs gt_max), stage-1
// labels, bbox regression targets; write out cols 0..4; build fg/bg histograms.
__global__ __launch_bounds__(256) void k_main(const float* gt, const float* im_info,
                                              const float* anchors, const int* fsp,
                                              const float* rand_fg, const float* rand_bg,
                                              float* out, Ws* ws) {
  __shared__ float sg[5][M_];
  __shared__ float sa[A_ * 4];
  __shared__ float sgm[M_];
  int tid = threadIdx.x;
  if (tid < M_) {
    float x1 = gt[tid * 5 + 0], y1 = gt[tid * 5 + 1];
    float x2 = gt[tid * 5 + 2], y2 = gt[tid * 5 + 3];
    sg[0][tid] = x1; sg[1][tid] = y1; sg[2][tid] = x2; sg[3][tid] = y2;
    sg[4][tid] = fM(fA(fS(x2, x1), 1.0f), fA(fS(y2, y1), 1.0f));
    int b = ws->gt_max_bits[tid];
    sgm[tid] = (b < 0) ? -1.0f : __int_as_float(b);
  }
  if (tid < A_ * 4) sa[tid] = anchors[tid];
  __syncthreads();

  int i = blockIdx.x * 256 + tid;
  if (i >= T_TOTAL) return;
  float fs = (float)fsp[0];
  float ax1, ay1, ax2, ay2;
  anchor_coords(i, sa, fs, ax1, ay1, ax2, ay2);
  float imh = im_info[0], imw = im_info[1];
  bool inside = (ax1 >= 0.0f) && (ay1 >= 0.0f) && (ax2 < imw) && (ay2 < imh);

  float bestv; int bestj = 0; bool isbest = false;
  if (inside) {
    float aarea = fM(fA(fS(ax2, ax1), 1.0f), fA(fS(ay2, ay1), 1.0f));
    bestv = -2.0f;
    for (int j = 0; j < M_; ++j) {
      float ov = iou_f(ax1, ay1, ax2, ay2, aarea,
                       sg[0][j], sg[1][j], sg[2][j], sg[3][j], sg[4][j]);
      if (ov > bestv) { bestv = ov; bestj = j; }  // strict > == first-index argmax
      if (ov == sgm[j]) isbest = true;
    }
  } else {
    bestv = -1.0f;
    for (int j = 0; j < M_; ++j)
      if (sgm[j] == -1.0f) isbest = true;
  }

  float lab = -1.0f;
  if (inside && bestv < 0.3f) lab = 0.0f;
  if (isbest) lab = 1.0f;
  if (inside && bestv >= 0.7f) lab = 1.0f;

  // targets (reference order of ops)
  float ew = fA(fS(ax2, ax1), 1.0f), eh = fA(fS(ay2, ay1), 1.0f);
  float ecx = fA(ax1, fM(0.5f, ew)), ecy = fA(ay1, fM(0.5f, eh));
  float g0 = sg[0][bestj], g1 = sg[1][bestj], g2 = sg[2][bestj], g3 = sg[3][bestj];
  float gw = fA(fS(g2, g0), 1.0f), gh = fA(fS(g3, g1), 1.0f);
  float gcx = fA(g0, fM(0.5f, gw)), gcy = fA(g1, fM(0.5f, gh));
  float t0 = fD(fS(gcx, ecx), ew);
  float t1 = fD(fS(gcy, ecy), eh);
  float t2 = logf(fD(gw, ew));
  float t3 = logf(fD(gh, eh));
  if (!inside) { t0 = 0.0f; t1 = 0.0f; t2 = 0.0f; t3 = 0.0f; }

  out[i * 7 + 0] = lab;
  out[i * 7 + 1] = t0;
  out[i * 7 + 2] = t1;
  out[i * 7 + 3] = t2;
  out[i * 7 + 4] = t3;

  if (lab == 1.0f) atomicAdd(&ws->hist_fg[bucket_of(rand_fg[i])], 1);
  if (lab == 0.0f) atomicAdd(&ws->hist_bg[bucket_of(rand_bg[i])], 1);
  unsigned long long mfg = __ballot(lab == 1.0f);
  unsigned long long mbg = __ballot(lab == 0.0f);
  if ((tid & 63) == 0) {
    if (mfg) atomicAdd(&ws->fg_count, __popcll(mfg));
    if (mbg) atomicAdd(&ws->bg_count, __popcll(mbg));
  }
}

// Find the histogram bucket containing the k-th (0-indexed) smallest value.
__global__ __launch_bounds__(256) void k_scan(Ws* ws) {
  __shared__ int part[256];
  int tid = threadIdx.x;
  int fgc = ws->fg_count, bgc = ws->bg_count;
  int kept_fg = fgc < KFG ? fgc : KFG;
  int kbg = BATCH - kept_fg;
  for (int pass = 0; pass < 2; ++pass) {
    const int* hist = pass == 0 ? ws->hist_fg : ws->hist_bg;
    int k = pass == 0 ? KFG : kbg;
    int cnt = pass == 0 ? fgc : bgc;
    int sum = 0;
    for (int b = 0; b < NBINS / 256; ++b) sum += hist[tid * (NBINS / 256) + b];
    part[tid] = sum;
    __syncthreads();
    if (tid == 0) {
      if (cnt > k) {  // selection needed; cutoff element is the k-th (0-indexed)
        int cum = 0, chunk = 0;
        for (int c = 0; c < 256; ++c) {
          if (cum + part[c] >= k + 1) { chunk = c; break; }
          cum += part[c];
        }
        int b = chunk * (NBINS / 256);
        for (int bb = chunk * (NBINS / 256); bb < (chunk + 1) * (NBINS / 256); ++bb) {
          if (cum + hist[bb] >= k + 1) { b = bb; break; }
          cum += hist[bb];
        }
        if (pass == 0) { ws->sel_fg = 1; ws->b_fg = b; ws->cb_fg = cum; }
        else           { ws->sel_bg = 1; ws->b_bg = b; ws->cb_bg = cum; }
      } else {
        if (pass == 0) { ws->sel_fg = 0; ws->b_fg = -1; ws->cb_fg = 0; }
        else           { ws->sel_bg = 0; ws->b_bg = -1; ws->cb_bg = 0; }
      }
      if (pass == 1) ws->k_bg = kbg;
    }
    __syncthreads();
  }
}

// Collect boundary-bucket elements (value, index) for exact tie-break ranking.
__global__ __launch_bounds__(256) void k_collect(const float* rand_fg, const float* rand_bg,
                                                 const float* out, Ws* ws) {
  int i = blockIdx.x * 256 + threadIdx.x;
  if (i >= T_TOTAL) return;
  float lab = out[i * 7];
  if (lab == 1.0f && ws->sel_fg) {
    float v = rand_fg[i];
    if (bucket_of(v) == ws->b_fg) {
      int p = atomicAdd(&ws->bnd_fg_n, 1);
      if (p < BCAP) { ws->bnd_fg_val[p] = v; ws->bnd_fg_idx[p] = i; }
    }
  }
  if (lab == 0.0f && ws->sel_bg) {
    float v = rand_bg[i];
    if (bucket_of(v) == ws->b_bg) {
      int p = atomicAdd(&ws->bnd_bg_n, 1);
      if (p < BCAP) { ws->bnd_bg_val[p] = v; ws->bnd_bg_idx[p] = i; }
    }
  }
}

// Exact r-th smallest (value, index) pair within the boundary bucket; weights.
__global__ __launch_bounds__(256) void k_cut(Ws* ws) {
  __shared__ float sv[BCAP];
  __shared__ int si[BCAP];
  int tid = threadIdx.x;
  for (int pass = 0; pass < 2; ++pass) {
    int sel = pass == 0 ? ws->sel_fg : ws->sel_bg;
    if (sel) {
      int n_raw = pass == 0 ? ws->bnd_fg_n : ws->bnd_bg_n;
      int n = n_raw < BCAP ? n_raw : BCAP;
      int r = pass == 0 ? (KFG - ws->cb_fg) : (ws->k_bg - ws->cb_bg);
      const float* bv = pass == 0 ? ws->bnd_fg_val : ws->bnd_bg_val;
      const int* bi = pass == 0 ? ws->bnd_fg_idx : ws->bnd_bg_idx;
      for (int e = tid; e < n; e += 256) { sv[e] = bv[e]; si[e] = bi[e]; }
      __syncthreads();
      if (r >= 0 && r < n) {
        for (int e = tid; e < n; e += 256) {
          float ve = sv[e]; int ie = si[e];
          int c = 0;
          for (int o = 0; o < n; ++o) {
            float vo = sv[o]; int io = si[o];
            if (vo < ve || (vo == ve && io < ie)) c++;
          }
          if (c == r) {  // exactly one element has lexicographic rank r
            if (pass == 0) { ws->cut_fg_val = ve; ws->cut_fg_idx = ie; }
            else           { ws->cut_bg_val = ve; ws->cut_bg_idx = ie; }
          }
        }
      }
      __syncthreads();
    }
  }
  if (tid == 0) {
    int kept_fg = ws->sel_fg ? KFG : ws->fg_count;
    int kept_bg = ws->sel_bg ? ws->k_bg : ws->bg_count;
    int ne = kept_fg + kept_bg;
    ws->wgt = (ne > 0) ? __fdiv_rn(1.0f, (float)(ne < 1 ? 1 : ne)) : 0.0f;
  }
}

// Apply subsampling cutoffs; write final labels + inside/outside weights.
__global__ __launch_bounds__(256) void k_final(const float* rand_fg, const float* rand_bg,
                                               float* out, Ws* ws) {
  int i = blockIdx.x * 256 + threadIdx.x;
  if (i >= T_TOTAL) return;
  float lab = out[i * 7];
  if (lab == 1.0f && ws->sel_fg) {
    float v = rand_fg[i];
    int b = bucket_of(v);
    float cv = ws->cut_fg_val; int ci = ws->cut_fg_idx;
    bool keep = (b < ws->b_fg) ||
                (b == ws->b_fg && (v < cv || (v == cv && i < ci)));
    if (!keep) lab = -1.0f;
  }
  if (lab == 0.0f && ws->sel_bg) {
    float v = rand_bg[i];
    int b = bucket_of(v);
    float cv = ws->cut_bg_val; int ci = ws->cut_bg_idx;
    bool keep = (b < ws->b_bg) ||
                (b == ws->b_bg && (v < cv || (v == cv && i < ci)));
    if (!keep) lab = -1.0f;
  }
  out[i * 7 + 0] = lab;
  out[i * 7 + 5] = (lab == 1.0f) ? 1.0f : 0.0f;
  out[i * 7 + 6] = (lab >= 0.0f) ? ws->wgt : 0.0f;
}

extern "C" void kernel_launch(void* const* d_in, const int* in_sizes, int n_in,
                              void* d_out, int out_size, void* d_ws, size_t ws_size,
                              hipStream_t stream) {
  const float* gt   = (const float*)d_in[1];
  const float* im   = (const float*)d_in[2];
  const float* anch = (const float*)d_in[3];
  const float* rfg  = (const float*)d_in[4];
  const float* rbg  = (const float*)d_in[5];
  const int*   fs   = (const int*)d_in[6];
  float* out = (float*)d_out;
  Ws* ws = (Ws*)d_ws;

  dim3 blk(256);
  int nb = (T_TOTAL + 255) / 256;  // 900
  k_init<<<17, blk, 0, stream>>>(ws);
  k_gtmax<<<nb, blk, 0, stream>>>(gt, im, anch, fs, ws);
  k_main<<<nb, blk, 0, stream>>>(gt, im, anch, fs, rfg, rbg, out, ws);
  k_scan<<<1, blk, 0, stream>>>(ws);
  k_collect<<<nb, blk, 0, stream>>>(rfg, rbg, out, ws);
  k_cut<<<1, blk, 0, stream>>>(ws);
  k_final<<<nb, blk, 0, stream>>>(rfg, rbg, out, ws);
}